// Round 9
// baseline (180.356 us; speedup 1.0000x reference)
//
#include <hip/hip_runtime.h>
#include <hip/hip_bf16.h>

typedef __attribute__((ext_vector_type(4))) float  float4v;
typedef __attribute__((ext_vector_type(4))) short  short4v;
typedef __attribute__((ext_vector_type(8))) short  short8v;
typedef __attribute__((ext_vector_type(8))) __bf16 bf16x8;

constexpr int E_NUM = 64;
constexpr int HID   = 64;
constexpr int DIN   = 1024;
constexpr int DOUT  = 1024;
constexpr int TPE   = 1024;

__device__ __forceinline__ short4v cvt4(float4v v) {
  short4v r;
#pragma unroll
  for (int j = 0; j < 4; j++) {
    __bf16 b = (__bf16)v[j];
    r[j] = __builtin_bit_cast(short, b);
  }
  return r;
}
__device__ __forceinline__ ushort cvt1(float f) {
  __bf16 b = (__bf16)f;
  return __builtin_bit_cast(ushort, b);
}

// ---------------------------------------------------------------------------
// Fused expert MLP: per block (expert e, 64-token row-block rb):
//   FC1: h = relu(X[64,1024] @ W1^T)  -- R7 structure (gload_lds fp32 dbuf,
//        counted vmcnt + raw barriers), h kept in LDS as swizzled bf16.
//   FC2: y[64,1024] = h @ W2^T        -- W2 streamed in 8 col-tiles through
//        the freed X buffers (L2-resident per XCD), acc in registers,
//        y stored NON-TEMPORAL at the end (keeps L3 free for X).
// LDS: 64+64+8 = 136KB -> 1 block/CU. grid = 64*16 = 1024, 512 threads.
// ---------------------------------------------------------------------------
__global__ __launch_bounds__(512, 2) void moe_fused_kernel(
    const float* __restrict__ x, const float* __restrict__ w1,
    const float* __restrict__ w2, float* __restrict__ y) {
  constexpr int BM = 64, BK = 128;
  __shared__ float  Xs[2][BM * BK];   // FC1 X dbuf; FC2 W2-tile dbuf
  __shared__ float  Wf[2][HID * BK];  // FC1 W1 dbuf
  __shared__ ushort hs[BM * HID];     // h bf16, unit-swizzled

  // XCD-bijective swizzle: nwg=1024; XCD k owns experts 8k..8k+7
  int nwg = (int)gridDim.x;
  int blk = (int)(blockIdx.x & 7) * (nwg >> 3) + (int)(blockIdx.x >> 3);
  int e  = blk >> 4;
  int rb = blk & 15;
  const float* xe  = x  + (size_t)(e * TPE + rb * BM) * DIN;
  const float* we1 = w1 + (size_t)e * HID * DIN;
  const float* we2 = w2 + (size_t)e * DOUT * HID;

  int tid  = (int)threadIdx.x;
  int lane = tid & 63;
  int wv   = tid >> 6;

  // ================= FC1 (verbatim R7 structure) =================
  int goff[4];
#pragma unroll
  for (int i = 0; i < 4; i++) {
    int j = wv * 4 + i;
    int r = 2 * j + (lane >> 5);
    int u = lane & 31;
    int p = (u >> 1) ^ (r & 15);
    goff[i] = r * DIN + p * 8 + (u & 1) * 4;
  }
  auto GLOAD1 = [&](int kt, int b) {
#pragma unroll
    for (int i = 0; i < 4; i++) {
      int j = wv * 4 + i;
      __builtin_amdgcn_global_load_lds(
          (__attribute__((address_space(1))) void*)(xe + goff[i] + kt),
          (__attribute__((address_space(3))) void*)(&Xs[b][j * 256]),
          16, 0, 0);
      __builtin_amdgcn_global_load_lds(
          (__attribute__((address_space(1))) void*)(we1 + goff[i] + kt),
          (__attribute__((address_space(3))) void*)(&Wf[b][j * 256]),
          16, 0, 0);
    }
  };

  int m16 = lane & 15;
  int kg  = (lane >> 4) * 8;
  int mf  = wv >> 1;
  int nb2 = (wv & 1) * 2;
  int ar  = mf * 16 + m16;

  float4v acc1[2];
#pragma unroll
  for (int j = 0; j < 2; j++)
#pragma unroll
    for (int q = 0; q < 4; q++) acc1[j][q] = 0.f;

  auto MMA1 = [&](int b) {
    const float* xb = &Xs[b][0];
    const float* wb = &Wf[b][0];
#pragma unroll
    for (int kk = 0; kk < BK; kk += 32) {
      int bi = (kk + kg) >> 3;
      int px = bi ^ (ar & 15);
      float4v x0 = *(const float4v*)(xb + ar * BK + px * 8);
      float4v x1 = *(const float4v*)(xb + ar * BK + px * 8 + 4);
      short4v a0 = cvt4(x0), a1 = cvt4(x1);
      short8v a;
#pragma unroll
      for (int q = 0; q < 4; q++) { a[q] = a0[q]; a[q + 4] = a1[q]; }
#pragma unroll
      for (int j = 0; j < 2; j++) {
        int br = (nb2 + j) * 16 + m16;
        int pw = bi ^ (br & 15);
        float4v w0 = *(const float4v*)(wb + br * BK + pw * 8);
        float4v w1v = *(const float4v*)(wb + br * BK + pw * 8 + 4);
        short4v b0 = cvt4(w0), b1 = cvt4(w1v);
        short8v bb;
#pragma unroll
        for (int q = 0; q < 4; q++) { bb[q] = b0[q]; bb[q + 4] = b1[q]; }
        acc1[j] = __builtin_amdgcn_mfma_f32_16x16x32_bf16(
            __builtin_bit_cast(bf16x8, a), __builtin_bit_cast(bf16x8, bb),
            acc1[j], 0, 0, 0);
      }
    }
  };

  GLOAD1(0, 0);
  GLOAD1(BK, 1);
#pragma unroll
  for (int s = 0; s < 8; s++) {
    if (s < 7) {
      asm volatile("s_waitcnt vmcnt(8)" ::: "memory");
    } else {
      asm volatile("s_waitcnt vmcnt(0)" ::: "memory");
    }
    __builtin_amdgcn_s_barrier();
    MMA1(s & 1);
    __builtin_amdgcn_s_barrier();
    if (s < 6) GLOAD1((s + 2) * BK, s & 1);
  }

  // h -> hs: relu, bf16, 16B-unit XOR swizzle (unit ^= row&7)
#pragma unroll
  for (int j = 0; j < 2; j++) {
    int col = (nb2 + j) * 16 + m16;
#pragma unroll
    for (int q = 0; q < 4; q++) {
      int row = mf * 16 + ((lane >> 4) << 2) + q;
      int idx = row * 64 + (((col >> 3) ^ (row & 7)) << 3) + (col & 7);
      hs[idx] = cvt1(fmaxf(acc1[j][q], 0.f));
    }
  }
  asm volatile("s_waitcnt lgkmcnt(0)" ::: "memory");
  __builtin_amdgcn_s_barrier();   // hs visible; FC1 vmem fully drained (s=7)

  // ================= FC2 =================
  // W2 tile nt = rows [nt*128, +128) x 64 floats (32KB) -> Xs[nt&1] via
  // gload_lds; 16B-unit source swizzle u ^= (row&15); LDS dest linear.
  int g2off[4];
#pragma unroll
  for (int i = 0; i < 4; i++) {
    int rl = (wv * 4 + i) * 4 + (lane >> 4);
    int u  = (lane & 15) ^ (rl & 15);
    g2off[i] = rl * HID + u * 4;
  }
  auto GLOAD2 = [&](int nt, float* buf) {
#pragma unroll
    for (int i = 0; i < 4; i++) {
      __builtin_amdgcn_global_load_lds(
          (__attribute__((address_space(1))) void*)(we2 + (size_t)nt * 128 * HID + g2off[i]),
          (__attribute__((address_space(3))) void*)(buf + (wv * 4 + i) * 256),
          16, 0, 0);
    }
  };

  int half4 = (wv & 1) * 4;
  float4v acc2[8][4];   // 128 VGPR: all 8 col-tiles accumulated, stored at end
#pragma unroll
  for (int t = 0; t < 8; t++)
#pragma unroll
    for (int nf = 0; nf < 4; nf++)
#pragma unroll
      for (int q = 0; q < 4; q++) acc2[t][nf][q] = 0.f;

  auto MMA2 = [&](float4v* accT, const float* buf) {
#pragma unroll
    for (int kk = 0; kk < 64; kk += 32) {
      int gk = kk + kg;
      short8v a = *(const short8v*)&hs[ar * 64 + (((gk >> 3) ^ (ar & 7)) << 3)];
#pragma unroll
      for (int nf = 0; nf < 4; nf++) {
        int o  = (half4 + nf) * 16 + m16;
        int u0 = (gk >> 2) ^ (o & 15);
        int u1 = ((gk >> 2) + 1) ^ (o & 15);
        float4v b0 = *(const float4v*)&buf[o * HID + u0 * 4];
        float4v b1 = *(const float4v*)&buf[o * HID + u1 * 4];
        short4v c0 = cvt4(b0), c1 = cvt4(b1);
        short8v bb;
#pragma unroll
        for (int q = 0; q < 4; q++) { bb[q] = c0[q]; bb[q + 4] = c1[q]; }
        accT[nf] = __builtin_amdgcn_mfma_f32_16x16x32_bf16(
            __builtin_bit_cast(bf16x8, a), __builtin_bit_cast(bf16x8, bb),
            accT[nf], 0, 0, 0);
      }
    }
  };

  GLOAD2(0, Xs[0]);
  GLOAD2(1, Xs[1]);
#pragma unroll
  for (int nt = 0; nt < 8; nt++) {
    if (nt < 7) {
      asm volatile("s_waitcnt vmcnt(4)" ::: "memory");   // tile nt done; nt+1 in flight
    } else {
      asm volatile("s_waitcnt vmcnt(0)" ::: "memory");
    }
    __builtin_amdgcn_s_barrier();
    MMA2(acc2[nt], (nt & 1) ? &Xs[1][0] : &Xs[0][0]);
    __builtin_amdgcn_s_barrier();
    if (nt < 6) GLOAD2(nt + 2, (nt & 1) ? &Xs[1][0] : &Xs[0][0]);
  }

  // ---- y stores: non-temporal (bypass/low-priority cache -> L3 stays X's) ----
  size_t ybase = (size_t)(e * TPE + rb * BM) * DOUT;
#pragma unroll
  for (int nt = 0; nt < 8; nt++) {
#pragma unroll
    for (int nf = 0; nf < 4; nf++) {
      int o = nt * 128 + (half4 + nf) * 16 + m16;
#pragma unroll
      for (int q = 0; q < 4; q++) {
        int row = mf * 16 + ((lane >> 4) << 2) + q;
        __builtin_nontemporal_store(acc2[nt][nf][q],
                                    &y[ybase + (size_t)row * DOUT + o]);
      }
    }
  }
}

extern "C" void kernel_launch(void* const* d_in, const int* in_sizes, int n_in,
                              void* d_out, int out_size, void* d_ws, size_t ws_size,
                              hipStream_t stream) {
  const float* x  = (const float*)d_in[0];
  // d_in[1] = fwd_expert_count: equal groups (T/E) by problem construction
  const float* w1 = (const float*)d_in[2];
  const float* w2 = (const float*)d_in[3];
  float* yout = (float*)d_out;

  moe_fused_kernel<<<E_NUM * 16, 512, 0, stream>>>(x, w1, w2, yout);
}

// Round 10
// 118.148 us; speedup vs baseline: 1.5265x; 1.5265x over previous
//
#include <hip/hip_runtime.h>
#include <hip/hip_bf16.h>

typedef __attribute__((ext_vector_type(4))) float  float4v;
typedef __attribute__((ext_vector_type(4))) short  short4v;
typedef __attribute__((ext_vector_type(8))) short  short8v;
typedef __attribute__((ext_vector_type(8))) __bf16 bf16x8;

constexpr int E_NUM = 64;
constexpr int HID   = 64;    // expert hidden
constexpr int DIN   = 1024;
constexpr int DOUT  = 1024;
constexpr int TPE   = 1024;  // tokens per expert = 65536/64

__device__ __forceinline__ short4v cvt4(float4v v) {
  short4v r;
#pragma unroll
  for (int j = 0; j < 4; j++) {
    __bf16 b = (__bf16)v[j];
    r[j] = __builtin_bit_cast(short, b);
  }
  return r;
}
__device__ __forceinline__ ushort cvt1(float f) {
  __bf16 b = (__bf16)f;
  return __builtin_bit_cast(ushort, b);
}

// ---------------------------------------------------------------------------
// Kernel 1 (FROZEN from round 5 -- best measured fc1):
// h[t, 0:64] = relu( x[t, :] @ W1[e]^T ), h stored bf16 in ws.
// BM=64 x BN=64, BK=256: 1KB contiguous row-slices per load instruction.
// 512 threads (8 waves), dbuf LDS 128KB, 1 barrier/step. grid = 1024.
// ---------------------------------------------------------------------------
__global__ __launch_bounds__(512, 2) void fc1_relu_kernel(
    const float* __restrict__ x, const float* __restrict__ w1,
    ushort* __restrict__ hbuf) {
  constexpr int BM = 64, BK = 256;
  __shared__ ushort Xs[2][BM * BK];   // 2 x 32KB, bf16 bits, XOR-swizzled
  __shared__ ushort Ws[2][HID * BK];  // 2 x 32KB

  int nwg = (int)gridDim.x;
  int blk = (int)(blockIdx.x & 7) * (nwg >> 3) + (int)(blockIdx.x >> 3);
  int e  = blk >> 4;
  int rb = blk & 15;
  const float* xe = x  + (size_t)(e * TPE + rb * BM) * DIN;
  const float* we = w1 + (size_t)e * HID * DIN;

  int tid  = (int)threadIdx.x;
  int lane = tid & 63;
  int wv   = tid >> 6;

  float4v xr[8], wr[8];

  auto LOAD = [&](int kt) {
#pragma unroll
    for (int i = 0; i < 8; i++) {
      int row = wv * 8 + i;   // one row per instruction: 1KB contiguous
      xr[i] = *(const float4v*)(xe + (size_t)row * DIN + kt + lane * 4);
      wr[i] = *(const float4v*)(we + (size_t)row * DIN + kt + lane * 4);
    }
  };
  auto WRITE = [&](ushort* Xb, ushort* Wb) {
#pragma unroll
    for (int i = 0; i < 8; i++) {
      int row = wv * 8 + i;
      int idx = (row * BK + lane * 4) ^ (i << 3);
      *(short4v*)&Xb[idx] = cvt4(xr[i]);
      *(short4v*)&Wb[idx] = cvt4(wr[i]);
    }
  };

  int mf  = wv >> 1;
  int nb2 = (wv & 1) * 2;
  int ar  = mf * 16 + (lane & 15);
  int kg  = (lane >> 4) * 8;

  float4v acc[2];
#pragma unroll
  for (int j = 0; j < 2; j++)
#pragma unroll
    for (int jj = 0; jj < 4; jj++) acc[j][jj] = 0.f;

  auto MMA = [&](const ushort* Xb, const ushort* Wb) {
#pragma unroll
    for (int kk = 0; kk < BK; kk += 32) {
      int k0 = kk + kg;
      short8v a = *(const short8v*)&Xb[(ar * BK + k0) ^ ((ar & 7) << 3)];
#pragma unroll
      for (int j = 0; j < 2; j++) {
        int br = (nb2 + j) * 16 + (lane & 15);
        short8v b = *(const short8v*)&Wb[(br * BK + k0) ^ ((br & 7) << 3)];
        acc[j] = __builtin_amdgcn_mfma_f32_16x16x32_bf16(
            __builtin_bit_cast(bf16x8, a), __builtin_bit_cast(bf16x8, b),
            acc[j], 0, 0, 0);
      }
    }
  };

  LOAD(0);
#pragma unroll
  for (int s = 0; s < 4; s++) {
    int buf = s & 1;
    WRITE(Xs[buf], Ws[buf]);
    __syncthreads();
    if (s < 3) LOAD((s + 1) * BK);
    MMA(Xs[buf], Ws[buf]);
  }

  ushort* hs = &Xs[0][0];   // 64x64 bf16 = 8KB
#pragma unroll
  for (int j = 0; j < 2; j++) {
    int col = (nb2 + j) * 16 + (lane & 15);
#pragma unroll
    for (int jj = 0; jj < 4; jj++) {
      int row = mf * 16 + ((lane >> 4) << 2) + jj;
      hs[row * HID + col] = cvt1(fmaxf(acc[j][jj], 0.f));
    }
  }
  __syncthreads();
  size_t rowbase = (size_t)e * TPE + rb * BM;
  int row = tid >> 3, c8 = (tid & 7) * 8;
  short8v v = *(const short8v*)&hs[row * HID + c8];
  *(short8v*)(hbuf + (rowbase + row) * HID + c8) = v;
}

// ---------------------------------------------------------------------------
// Kernel 2: y[t, o] = h[t, :] @ W2[e]^T. Single K=64 pass.
// NEW epilogue: acc -> LDS transpose (reuse Hs/Ws region, 2 passes of 64
// rows) -> contiguous 16B/lane NON-TEMPORAL dwordx4 stores. y bypasses L3
// (keeps X resident for fc1); write pattern matches fillBuffer's 6.9 TB/s.
// grid = 64 experts * 8 * 8 = 4096, 256 threads, 32KB LDS.
// ---------------------------------------------------------------------------
__global__ __launch_bounds__(256) void fc2_kernel(
    const ushort* __restrict__ hbuf, const float* __restrict__ w2,
    float* __restrict__ y) {
  constexpr int BM = 128, BN = 128, K = 64;
  __shared__ __align__(16) ushort smem[BM * K + BN * K];   // 32KB
  ushort* Hs = smem;
  ushort* Ws = smem + BM * K;

  int nwg = (int)gridDim.x;  // 4096, divisible by 8
  int blk = (int)(blockIdx.x & 7) * (nwg >> 3) + (int)(blockIdx.x >> 3);

  int e  = blk >> 6;
  int mb = (blk >> 3) & 7;
  int nb = blk & 7;
  const ushort* he = hbuf + (size_t)(e * TPE + mb * BM) * K;
  const float*  we = w2 + ((size_t)e * DOUT + nb * BN) * K;

  int tid  = (int)threadIdx.x;
  int lane = tid & 63;
  int wv   = tid >> 6;

  // stage H: 128x64 bf16 (1024 chunks of 16B, fully contiguous region)
#pragma unroll
  for (int i = 0; i < 4; i++) {
    int f = tid + i * 256;
    int row = f >> 3, c8 = f & 7;
    short8v v = *(const short8v*)(he + (size_t)row * K + c8 * 8);
    *(short8v*)&Hs[(row * K + c8 * 8) ^ ((row & 7) << 3)] = v;
  }
  // stage W2: 128x64 fp32 -> bf16 (2048 float4 chunks, contiguous region)
#pragma unroll
  for (int i = 0; i < 8; i++) {
    int f = tid + i * 256;
    int row = f >> 4, c4 = f & 15;
    float4v v = *(const float4v*)(we + (size_t)row * K + c4 * 4);
    *(short4v*)&Ws[(row * K + c4 * 4) ^ ((row & 7) << 3)] = cvt4(v);
  }
  __syncthreads();

  float4v acc[2][8];
#pragma unroll
  for (int mf = 0; mf < 2; mf++)
#pragma unroll
    for (int nf = 0; nf < 8; nf++)
#pragma unroll
      for (int j = 0; j < 4; j++) acc[mf][nf][j] = 0.f;

  int kg = (lane >> 4) * 8;
#pragma unroll
  for (int kk = 0; kk < K; kk += 32) {
    int k0 = kk + kg;
    short8v a[2];
#pragma unroll
    for (int mf = 0; mf < 2; mf++) {
      int arr = wv * 32 + mf * 16 + (lane & 15);
      a[mf] = *(const short8v*)&Hs[(arr * K + k0) ^ ((arr & 7) << 3)];
    }
#pragma unroll
    for (int nf = 0; nf < 8; nf++) {
      int br = nf * 16 + (lane & 15);
      short8v b = *(const short8v*)&Ws[(br * K + k0) ^ ((br & 7) << 3)];
#pragma unroll
      for (int mf = 0; mf < 2; mf++)
        acc[mf][nf] = __builtin_amdgcn_mfma_f32_16x16x32_bf16(
            __builtin_bit_cast(bf16x8, a[mf]), __builtin_bit_cast(bf16x8, b),
            acc[mf][nf], 0, 0, 0);
    }
  }

  // ---- epilogue: 2 passes of 64 rows through LDS (Hs/Ws are dead) ----
  // Block rows 0-63 owned by waves 0,1; rows 64-127 by waves 2,3.
  float* Yt = (float*)smem;   // 64 x 128 fp32 = 32KB
  size_t rowbase = (size_t)(e * TPE + mb * BM);
  int col0 = nb * BN;
#pragma unroll
  for (int pass = 0; pass < 2; pass++) {
    __syncthreads();   // pass0: Hs/Ws reads done; pass1: prev stores read out
    if ((wv >> 1) == pass) {
      int lrow0 = (wv & 1) * 32;
#pragma unroll
      for (int mf = 0; mf < 2; mf++) {
#pragma unroll
        for (int j = 0; j < 4; j++) {
          int lrow = lrow0 + mf * 16 + ((lane >> 4) << 2) + j;
#pragma unroll
          for (int nf = 0; nf < 8; nf++)
            Yt[lrow * BN + nf * 16 + (lane & 15)] = acc[mf][nf][j];
        }
      }
    }
    __syncthreads();
    // cooperative non-temporal store: 2048 chunks of 16B, 8 per thread
#pragma unroll
    for (int i = 0; i < 8; i++) {
      int idx  = tid + i * 256;
      int lrow = idx >> 5;            // 32 chunks per row (128 floats)
      int c4   = idx & 31;
      float4v v = *(const float4v*)&Yt[lrow * BN + c4 * 4];
      float* dst = y + (rowbase + pass * 64 + lrow) * DOUT + col0 + c4 * 4;
      __builtin_nontemporal_store(v, (float4v*)dst);
    }
  }
}

extern "C" void kernel_launch(void* const* d_in, const int* in_sizes, int n_in,
                              void* d_out, int out_size, void* d_ws, size_t ws_size,
                              hipStream_t stream) {
  const float* x  = (const float*)d_in[0];
  // d_in[1] = fwd_expert_count: equal groups (T/E) by problem construction
  const float* w1 = (const float*)d_in[2];
  const float* w2 = (const float*)d_in[3];
  float* yout = (float*)d_out;
  ushort* hbuf = (ushort*)d_ws;   // T * 64 bf16 = 8.4 MB scratch

  fc1_relu_kernel<<<E_NUM * 16, 512, 0, stream>>>(x, w1, hbuf);
  fc2_kernel<<<E_NUM * 64, 256, 0, stream>>>(hbuf, w2, yout);
}